// Round 12
// baseline (92.675 us; speedup 1.0000x reference)
//
#include <hip/hip_runtime.h>

// Bidirectional NN-MSE via MFMA — R12: diagnostic partition. Same total issued
// work as R9 (best so far), repartitioned to QT=1 / SSPLIT=4 so nn_part's
// duration crosses the harness-fill threshold (41 us) into the rocprof top-5:
// 8 structural variants were all neutral and nn_part has been counter-invisible
// since R5. 64 iterations/wave also tests partition-independence of the ~33 us
// plateau (if latency/concurrency-bound, fewer resident waves => longer).
//
//   loss = w * mean_n min_j ||p_n - g_j||^2 + (1-w) * mean_m min_i ||g_m - p_i||^2
//
// d^2 = qq - 2 q.r + rr inside mfma_f32_32x32x16_bf16 (K=16), 2-term bf16
// split per operand (exact bf16xbf16 products; absmax 0 R2-R11).

#define NPTS   16384
#define QBLK   128                // 4 waves x 32 queries (QT=1)
#define QCH    (NPTS / QBLK)      // 128 query chunks
#define SSPLIT 4                  // ref splits
#define RBLK   (NPTS / SSPLIT)    // 4096 refs streamed per block (128 tiles)
#define NB1    (2 * QCH * SSPLIT) // 1024 blocks

typedef __attribute__((ext_vector_type(8)))  __bf16 bf16x8;
typedef __attribute__((ext_vector_type(16))) float  floatx16;

union frag16 { __bf16 v[16]; uint4 q[2]; };

__device__ __forceinline__ float vmin16(floatx16 v) {
    float a = fminf(fminf(v[0], v[1]), v[2]);
    float b = fminf(fminf(v[3], v[4]), v[5]);
    float c = fminf(fminf(v[6], v[7]), v[8]);
    float d = fminf(fminf(v[9], v[10]), v[11]);
    float e = fminf(fminf(v[12], v[13]), fminf(v[14], v[15]));
    return fminf(fminf(fminf(a, b), fminf(c, d)), e);
}

// One thread per (role, point): builds A-form (ref) and B-form (query)
// fragments. A-form pre-swizzled in MFMA wave order: uint4 index
// (p>>5)*64 + half*32 + (p&31) -> each wave tile read is one contiguous,
// perfectly-coalesced 1 KB global_load_dwordx4 burst.
__global__ __launch_bounds__(256) void prep_kernel(
    const float* __restrict__ pred, const float* __restrict__ gt,
    uint4* __restrict__ aform, uint4* __restrict__ bform,
    float* __restrict__ out)
{
    const int i = blockIdx.x * 256 + threadIdx.x;   // 0 .. 2*NPTS-1
    if (i == 0) out[0] = 0.0f;
    const int role = (i < NPTS) ? 0 : 1;            // 0=pred, 1=gt
    const int p = i - role * NPTS;
    const float* __restrict__ src = role ? gt : pred;

    const float x = src[p * 3 + 0], y = src[p * 3 + 1], z = src[p * 3 + 2];
    const float nn = x * x + y * y + z * z;
    const __bf16 xh = (__bf16)x, yh = (__bf16)y, zh = (__bf16)z;
    const __bf16 xl = (__bf16)(x - (float)xh);
    const __bf16 yl = (__bf16)(y - (float)yh);
    const __bf16 zl = (__bf16)(z - (float)zh);
    const __bf16 nh = (__bf16)nn;
    const __bf16 nl = (__bf16)(nn - (float)nh);
    const __bf16 one = (__bf16)1.0f;

    frag16 A;
    A.v[0]  = (__bf16)(-2.0f * (float)xh); A.v[1]  = A.v[0];
    A.v[2]  = (__bf16)(-2.0f * (float)xl); A.v[3]  = A.v[2];
    A.v[4]  = (__bf16)(-2.0f * (float)yh); A.v[5]  = A.v[4];
    A.v[6]  = (__bf16)(-2.0f * (float)yl); A.v[7]  = A.v[6];
    A.v[8]  = (__bf16)(-2.0f * (float)zh); A.v[9]  = A.v[8];
    A.v[10] = (__bf16)(-2.0f * (float)zl); A.v[11] = A.v[10];
    A.v[12] = nh;  A.v[13] = nl;  A.v[14] = one;  A.v[15] = one;

    frag16 B;
    B.v[0] = xh;  B.v[1]  = xl;  B.v[2]  = xh;  B.v[3]  = xl;
    B.v[4] = yh;  B.v[5]  = yl;  B.v[6]  = yh;  B.v[7]  = yl;
    B.v[8] = zh;  B.v[9]  = zl;  B.v[10] = zh;  B.v[11] = zl;
    B.v[12] = one; B.v[13] = one; B.v[14] = nh;  B.v[15] = nl;

    uint4* da = aform + (size_t)role * (NPTS * 2)
              + ((p >> 5) * 64 + (p & 31));
    da[0]  = A.q[0];        // half 0 (k=0..7)  at +0
    da[32] = A.q[1];        // half 1 (k=8..15) at +32
    uint4* db = bform + (size_t)role * (NPTS * 2) + p * 2;
    db[0] = B.q[0];
    db[1] = B.q[1];
}

__global__ __launch_bounds__(256) void nn_part_kernel(
    const uint4* __restrict__ aform, const uint4* __restrict__ bform,
    float* __restrict__ partial)
{
    const int bx   = blockIdx.x;           // 0..NB1-1
    const int dir  = bx >> 9;              // 0: Q=pred,R=gt ; 1: Q=gt,R=pred
    const int qc   = (bx & 511) >> 2;      // 0..127
    const int s    = bx & 3;               // 0..3
    const int tid  = threadIdx.x;
    const int lane = tid & 63;
    const int wave = tid >> 6;
    const int lid  = lane & 31;
    const int half = lane >> 5;

    // dir 0: queries=pred(role 0), refs=gt(role 1); dir 1 swapped
    const uint4* __restrict__ Aref = aform + (size_t)(dir ? 0 : 1) * (NPTS * 2);
    const uint4* __restrict__ Bqry = bform + (size_t)(dir ? 1 : 0) * (NPTS * 2);

    // ---- query B-fragment (prebuilt, 16 B/lane) ----
    const int qbase = qc * QBLK + wave * 32;
    const bf16x8 bq = __builtin_bit_cast(bf16x8, Bqry[(qbase + lid) * 2 + half]);

    floatx16 zero;
#pragma unroll
    for (int k = 0; k < 16; ++k) zero[k] = 0.0f;
    floatx16 mnv;
#pragma unroll
    for (int k = 0; k < 16; ++k) mnv[k] = 3.4e38f;

    // ---- hot loop: stream A-frags from L2, intrinsic MFMA, unroll 4 ----
    // per iteration: 2 coalesced 1 KB global_load_dwordx4 bursts, 2 MFMA,
    // 16 v_min3. unroll 4 -> up to 8 loads in flight, compiler-scheduled.
    const uint4* gp = Aref + (size_t)s * (RBLK * 2) + half * 32 + lid;
#pragma unroll 4
    for (int t = 0; t < RBLK / 32; t += 2) {
        const bf16x8 a0 = __builtin_bit_cast(bf16x8, gp[t * 64]);
        const bf16x8 a1 = __builtin_bit_cast(bf16x8, gp[t * 64 + 64]);
        floatx16 d0 = __builtin_amdgcn_mfma_f32_32x32x16_bf16(a0, bq, zero, 0, 0, 0);
        floatx16 d1 = __builtin_amdgcn_mfma_f32_32x32x16_bf16(a1, bq, zero, 0, 0, 0);
#pragma unroll
        for (int k = 0; k < 16; ++k)       // 16 independent v_min3 chains
            mnv[k] = fminf(fminf(mnv[k], d0[k]), d1[k]);
    }

    // ---- tail: in-lane tree + one shuffle, plain coalesced store ----
    float v = vmin16(mnv);
    v = fminf(v, __shfl_xor(v, 32));
    if (half == 0) {
        float* pout = partial + ((size_t)((dir * QCH + qc) * SSPLIT + s)) * QBLK
                    + wave * 32;
        pout[lid] = v;
    }
}

// Combine: min over the SSPLIT ref-splits per query, weighted sum into out.
__global__ __launch_bounds__(QBLK) void nn_combine_kernel(
    const float* __restrict__ partial, const float* __restrict__ weight,
    float* __restrict__ out)
{
    const int b   = blockIdx.x;        // 0..2*QCH-1
    const int dir = b >> 7;
    const int qc  = b & 127;
    const int t   = threadIdx.x;       // 0..127

    const float* p = partial + ((size_t)((dir * QCH + qc) * SSPLIT)) * QBLK;
    float v = p[t];
#pragma unroll
    for (int s = 1; s < SSPLIT; ++s)
        v = fminf(v, p[s * QBLK + t]);

    for (int off = 32; off; off >>= 1) v += __shfl_down(v, off);
    __shared__ float ws[2];
    if ((t & 63) == 0) ws[t >> 6] = v;
    __syncthreads();
    if (t == 0) {
        const float sum = ws[0] + ws[1];
        const float wgt = weight[0];
        const float scale = (dir ? (1.0f - wgt) : wgt) / (3.0f * (float)NPTS);
        atomicAdd(out, sum * scale);
    }
}

extern "C" void kernel_launch(void* const* d_in, const int* in_sizes, int n_in,
                              void* d_out, int out_size, void* d_ws, size_t ws_size,
                              hipStream_t stream) {
    const float* pred   = (const float*)d_in[0];
    const float* gt     = (const float*)d_in[1];
    const float* weight = (const float*)d_in[2];

    // ws: [partial 512 KB][aform 1 MB][bform 1 MB]
    float* partial = (float*)d_ws;                       // 2*QCH*SSPLIT*QBLK f32
    uint4* aform = (uint4*)((char*)d_ws + (size_t)2 * QCH * SSPLIT * QBLK * 4);
    uint4* bform = aform + (size_t)2 * NPTS * 2;

    prep_kernel<<<2 * NPTS / 256, 256, 0, stream>>>(pred, gt, aform, bform,
                                                    (float*)d_out);
    nn_part_kernel<<<NB1, 256, 0, stream>>>(aform, bform, partial);
    nn_combine_kernel<<<2 * QCH, QBLK, 0, stream>>>(partial, weight, (float*)d_out);
}

// Round 13
// 81.620 us; speedup vs baseline: 1.1354x; 1.1354x over previous
//
#include <hip/hip_runtime.h>

// Bidirectional NN-MSE via MFMA — R13: QT=2 with R11's bloat-free asm block
// applied per query-fragment -> 512 B of L2 A-stream per MFMA (halves R11/R12's
// 1 KB/MFMA). R12 showed duration tracks L2 traffic (+6 us for +268 MB).
//
//   loss = w * mean_n min_j ||p_n - g_j||^2 + (1-w) * mean_m min_i ||g_m - p_i||^2
//
// d^2 = qq - 2 q.r + rr inside mfma_f32_32x32x16_bf16 (K=16), 2-term bf16
// split per operand (exact bf16xbf16 products; absmax 0 R2-R12).

#define NPTS   16384
#define QBLK   256                // 4 waves x 2 tiles x 32 queries (QT=2)
#define QCH    (NPTS / QBLK)      // 64 query chunks
#define SSPLIT 8                  // ref splits
#define RBLK   (NPTS / SSPLIT)    // 2048 refs streamed per block (64 tiles)
#define NB1    (2 * QCH * SSPLIT) // 1024 blocks

typedef __attribute__((ext_vector_type(8)))  __bf16 bf16x8;
typedef __attribute__((ext_vector_type(16))) float  floatx16;

union frag16 { __bf16 v[16]; uint4 q[2]; };

// One thread per (role, point): builds A-form (ref) and B-form (query)
// fragments. A-form pre-swizzled in MFMA wave order: uint4 index
// (p>>5)*64 + half*32 + (p&31) -> each wave tile read is one contiguous,
// perfectly-coalesced 1 KB global_load_dwordx4 burst.
__global__ __launch_bounds__(256) void prep_kernel(
    const float* __restrict__ pred, const float* __restrict__ gt,
    uint4* __restrict__ aform, uint4* __restrict__ bform,
    float* __restrict__ out)
{
    const int i = blockIdx.x * 256 + threadIdx.x;   // 0 .. 2*NPTS-1
    if (i == 0) out[0] = 0.0f;
    const int role = (i < NPTS) ? 0 : 1;            // 0=pred, 1=gt
    const int p = i - role * NPTS;
    const float* __restrict__ src = role ? gt : pred;

    const float x = src[p * 3 + 0], y = src[p * 3 + 1], z = src[p * 3 + 2];
    const float nn = x * x + y * y + z * z;
    const __bf16 xh = (__bf16)x, yh = (__bf16)y, zh = (__bf16)z;
    const __bf16 xl = (__bf16)(x - (float)xh);
    const __bf16 yl = (__bf16)(y - (float)yh);
    const __bf16 zl = (__bf16)(z - (float)zh);
    const __bf16 nh = (__bf16)nn;
    const __bf16 nl = (__bf16)(nn - (float)nh);
    const __bf16 one = (__bf16)1.0f;

    frag16 A;
    A.v[0]  = (__bf16)(-2.0f * (float)xh); A.v[1]  = A.v[0];
    A.v[2]  = (__bf16)(-2.0f * (float)xl); A.v[3]  = A.v[2];
    A.v[4]  = (__bf16)(-2.0f * (float)yh); A.v[5]  = A.v[4];
    A.v[6]  = (__bf16)(-2.0f * (float)yl); A.v[7]  = A.v[6];
    A.v[8]  = (__bf16)(-2.0f * (float)zh); A.v[9]  = A.v[8];
    A.v[10] = (__bf16)(-2.0f * (float)zl); A.v[11] = A.v[10];
    A.v[12] = nh;  A.v[13] = nl;  A.v[14] = one;  A.v[15] = one;

    frag16 B;
    B.v[0] = xh;  B.v[1]  = xl;  B.v[2]  = xh;  B.v[3]  = xl;
    B.v[4] = yh;  B.v[5]  = yl;  B.v[6]  = yh;  B.v[7]  = yl;
    B.v[8] = zh;  B.v[9]  = zl;  B.v[10] = zh;  B.v[11] = zl;
    B.v[12] = one; B.v[13] = one; B.v[14] = nh;  B.v[15] = nl;

    uint4* da = aform + (size_t)role * (NPTS * 2)
              + ((p >> 5) * 64 + (p & 31));
    da[0]  = A.q[0];        // half 0 (k=0..7)  at +0
    da[32] = A.q[1];        // half 1 (k=8..15) at +32
    uint4* db = bform + (size_t)role * (NPTS * 2) + p * 2;
    db[0] = B.q[0];
    db[1] = B.q[1];
}

// R11's proven asm block: 2 MFMA into fixed dest banks + 16 v_min3 into
// "+v"-pinned accumulators. Emitted once per query-fragment per tile-pair.
#define MFMA_MIN_BLOCK(BQ, M)                                               \
    asm volatile(                                                           \
        "v_mfma_f32_32x32x16_bf16 v[32:47], %[A0], %[B], %[Z]\n\t"          \
        "v_mfma_f32_32x32x16_bf16 v[48:63], %[A1], %[B], %[Z]\n\t"          \
        "s_nop 7\n\ts_nop 7\n\ts_nop 7\n\ts_nop 7\n\t"                      \
        "v_min3_f32 %[M0],  %[M0],  v32, v48\n\t"                           \
        "v_min3_f32 %[M1],  %[M1],  v33, v49\n\t"                           \
        "v_min3_f32 %[M2],  %[M2],  v34, v50\n\t"                           \
        "v_min3_f32 %[M3],  %[M3],  v35, v51\n\t"                           \
        "v_min3_f32 %[M4],  %[M4],  v36, v52\n\t"                           \
        "v_min3_f32 %[M5],  %[M5],  v37, v53\n\t"                           \
        "v_min3_f32 %[M6],  %[M6],  v38, v54\n\t"                           \
        "v_min3_f32 %[M7],  %[M7],  v39, v55\n\t"                           \
        "v_min3_f32 %[M8],  %[M8],  v40, v56\n\t"                           \
        "v_min3_f32 %[M9],  %[M9],  v41, v57\n\t"                           \
        "v_min3_f32 %[M10], %[M10], v42, v58\n\t"                           \
        "v_min3_f32 %[M11], %[M11], v43, v59\n\t"                           \
        "v_min3_f32 %[M12], %[M12], v44, v60\n\t"                           \
        "v_min3_f32 %[M13], %[M13], v45, v61\n\t"                           \
        "v_min3_f32 %[M14], %[M14], v46, v62\n\t"                           \
        "v_min3_f32 %[M15], %[M15], v47, v63"                               \
        : [M0] "+v"(M[0]),  [M1] "+v"(M[1]),  [M2] "+v"(M[2]),              \
          [M3] "+v"(M[3]),  [M4] "+v"(M[4]),  [M5] "+v"(M[5]),              \
          [M6] "+v"(M[6]),  [M7] "+v"(M[7]),  [M8] "+v"(M[8]),              \
          [M9] "+v"(M[9]),  [M10] "+v"(M[10]), [M11] "+v"(M[11]),           \
          [M12] "+v"(M[12]), [M13] "+v"(M[13]), [M14] "+v"(M[14]),          \
          [M15] "+v"(M[15])                                                 \
        : [A0] "v"(a0), [A1] "v"(a1), [B] "v"(BQ), [Z] "v"(zero)            \
        : "v32", "v33", "v34", "v35", "v36", "v37", "v38", "v39",           \
          "v40", "v41", "v42", "v43", "v44", "v45", "v46", "v47",           \
          "v48", "v49", "v50", "v51", "v52", "v53", "v54", "v55",           \
          "v56", "v57", "v58", "v59", "v60", "v61", "v62", "v63")

__global__ __launch_bounds__(256) void nn_part_kernel(
    const uint4* __restrict__ aform, const uint4* __restrict__ bform,
    float* __restrict__ partial)
{
    const int bx   = blockIdx.x;           // 0..NB1-1
    const int dir  = bx >> 9;              // 0: Q=pred,R=gt ; 1: Q=gt,R=pred
    const int qc   = (bx & 511) >> 3;      // 0..63
    const int s    = bx & 7;               // 0..7
    const int tid  = threadIdx.x;
    const int lane = tid & 63;
    const int wave = tid >> 6;
    const int lid  = lane & 31;
    const int half = lane >> 5;

    // dir 0: queries=pred(role 0), refs=gt(role 1); dir 1 swapped
    const uint4* __restrict__ Aref = aform + (size_t)(dir ? 0 : 1) * (NPTS * 2);
    const uint4* __restrict__ Bqry = bform + (size_t)(dir ? 1 : 0) * (NPTS * 2);

    // ---- two query B-fragments per wave (prebuilt, 16 B/lane) ----
    const int qbase = qc * QBLK + wave * 64;
    const bf16x8 bq0 = __builtin_bit_cast(bf16x8, Bqry[(qbase + lid) * 2 + half]);
    const bf16x8 bq1 = __builtin_bit_cast(bf16x8, Bqry[(qbase + 32 + lid) * 2 + half]);

    floatx16 zero;
#pragma unroll
    for (int k = 0; k < 16; ++k) zero[k] = 0.0f;

    float ma[16], mb[16];
#pragma unroll
    for (int k = 0; k < 16; ++k) { ma[k] = 3.4e38f; mb[k] = 3.4e38f; }

    // ---- hot loop: 2 KB A-stream feeds 4 MFMAs (512 B/MFMA) ----
    const uint4* gp = Aref + (size_t)s * (RBLK * 2) + half * 32 + lid;
#pragma unroll 2
    for (int t = 0; t < RBLK / 32; t += 2) {
        const bf16x8 a0 = __builtin_bit_cast(bf16x8, gp[t * 64]);
        const bf16x8 a1 = __builtin_bit_cast(bf16x8, gp[t * 64 + 64]);
        MFMA_MIN_BLOCK(bq0, ma);
        MFMA_MIN_BLOCK(bq1, mb);
    }

    // ---- tail: in-lane trees + one shuffle each, plain coalesced store ----
    float* pout = partial + ((size_t)((dir * QCH + qc) * SSPLIT + s)) * QBLK
                + wave * 64;
    {
        float a = fminf(fminf(ma[0], ma[1]), fminf(ma[2], ma[3]));
        float b = fminf(fminf(ma[4], ma[5]), fminf(ma[6], ma[7]));
        float c = fminf(fminf(ma[8], ma[9]), fminf(ma[10], ma[11]));
        float d = fminf(fminf(ma[12], ma[13]), fminf(ma[14], ma[15]));
        float v = fminf(fminf(a, b), fminf(c, d));
        v = fminf(v, __shfl_xor(v, 32));
        if (half == 0) pout[lid] = v;
    }
    {
        float a = fminf(fminf(mb[0], mb[1]), fminf(mb[2], mb[3]));
        float b = fminf(fminf(mb[4], mb[5]), fminf(mb[6], mb[7]));
        float c = fminf(fminf(mb[8], mb[9]), fminf(mb[10], mb[11]));
        float d = fminf(fminf(mb[12], mb[13]), fminf(mb[14], mb[15]));
        float v = fminf(fminf(a, b), fminf(c, d));
        v = fminf(v, __shfl_xor(v, 32));
        if (half == 0) pout[32 + lid] = v;
    }
}

// Combine: min over the SSPLIT ref-splits per query, weighted sum into out.
__global__ __launch_bounds__(256) void nn_combine_kernel(
    const float* __restrict__ partial, const float* __restrict__ weight,
    float* __restrict__ out)
{
    const int b   = blockIdx.x;        // 0..127 : dir = b>>6, qc = b&63
    const int dir = b >> 6;
    const int qc  = b & 63;
    const int t   = threadIdx.x;

    const float* p = partial + ((size_t)((dir * QCH + qc) * SSPLIT)) * QBLK;
    float v = p[t];
#pragma unroll
    for (int s = 1; s < SSPLIT; ++s)
        v = fminf(v, p[s * QBLK + t]);

    for (int off = 32; off; off >>= 1) v += __shfl_down(v, off);
    __shared__ float ws[4];
    if ((t & 63) == 0) ws[t >> 6] = v;
    __syncthreads();
    if (t == 0) {
        const float sum = ws[0] + ws[1] + ws[2] + ws[3];
        const float wgt = weight[0];
        const float scale = (dir ? (1.0f - wgt) : wgt) / (3.0f * (float)NPTS);
        atomicAdd(out, sum * scale);
    }
}

extern "C" void kernel_launch(void* const* d_in, const int* in_sizes, int n_in,
                              void* d_out, int out_size, void* d_ws, size_t ws_size,
                              hipStream_t stream) {
    const float* pred   = (const float*)d_in[0];
    const float* gt     = (const float*)d_in[1];
    const float* weight = (const float*)d_in[2];

    // ws: [partial 512 KB][aform 1 MB][bform 1 MB]
    float* partial = (float*)d_ws;                       // 2*QCH*SSPLIT*QBLK f32
    uint4* aform = (uint4*)((char*)d_ws + (size_t)2 * QCH * SSPLIT * QBLK * 4);
    uint4* bform = aform + (size_t)2 * NPTS * 2;

    prep_kernel<<<2 * NPTS / 256, 256, 0, stream>>>(pred, gt, aform, bform,
                                                    (float*)d_out);
    nn_part_kernel<<<NB1, 256, 0, stream>>>(aform, bform, partial);
    nn_combine_kernel<<<2 * QCH, 256, 0, stream>>>(partial, weight, (float*)d_out);
}